// Round 1
// baseline (362.248 us; speedup 1.0000x reference)
//
#include <hip/hip_runtime.h>
#include <hip/hip_bf16.h>
#include <stdint.h>

#define NB 4096
#define ND 256
#define NC 32000

typedef __bf16 bf16x8 __attribute__((ext_vector_type(8)));
typedef float  f32x4  __attribute__((ext_vector_type(4)));

#define GLDS16(g, l)                                                          \
  __builtin_amdgcn_global_load_lds(                                           \
      (const __attribute__((address_space(1))) void*)(g),                     \
      (__attribute__((address_space(3))) void*)(l), 16, 0, 0)

__device__ __forceinline__ unsigned short f32_to_bf16(float f) {
  union { float f; uint32_t u; } v; v.f = f;
  uint32_t r = v.u + 0x7fffu + ((v.u >> 16) & 1u);
  return (unsigned short)(r >> 16);
}

// Cast inputs/V to bf16 in workspace; zero rowsum + loss accumulator.
__global__ void prep_kernel(const float* __restrict__ inA,
                            const float* __restrict__ inV,
                            unsigned short* __restrict__ outA,
                            unsigned short* __restrict__ outV,
                            float* __restrict__ rowsum,
                            float* __restrict__ loss) {
  int gid = blockIdx.x * blockDim.x + threadIdx.x;
  int stride = gridDim.x * blockDim.x;
  if (gid == 0) *loss = 0.f;
  for (int i = gid; i < NB; i += stride) rowsum[i] = 0.f;
  const int nA4 = NB * ND / 4;   // 262144
  const int nV4 = NC * ND / 4;   // 2048000
  for (int i = gid; i < nA4 + nV4; i += stride) {
    float4 v = (i < nA4) ? ((const float4*)inA)[i]
                         : ((const float4*)inV)[i - nA4];
    ushort4 o;
    o.x = f32_to_bf16(v.x);
    o.y = f32_to_bf16(v.y);
    o.z = f32_to_bf16(v.z);
    o.w = f32_to_bf16(v.w);
    if (i < nA4) ((ushort4*)outA)[i] = o;
    else         ((ushort4*)outV)[i - nA4] = o;
  }
}

// 128x128 tile, BK=32, 4 waves (2x2), each wave 64x64 via 4x4 mfma 16x16x32.
// A [4096][256] bf16 row-major; V [32000][256] bf16 row-major (NT gemm).
// Epilogue: write out[row][col] (f32) and atomicAdd per-row sum(exp(v)).
__global__ void __launch_bounds__(256)
gemm_expsum_kernel(const unsigned short* __restrict__ A,
                   const unsigned short* __restrict__ V,
                   float* __restrict__ out,     // d_out + 1
                   float* __restrict__ rowsum) {
  __shared__ unsigned short As[128 * 32];
  __shared__ unsigned short Bs[128 * 32];

  const int tid  = threadIdx.x;
  const int lane = tid & 63;
  const int wave = tid >> 6;
  const int wr   = wave >> 1;      // wave row quadrant (0/1)
  const int wc   = wave & 1;       // wave col quadrant (0/1)
  const int c16  = lane & 15;
  const int kq   = lane >> 4;      // 0..3

  const int brow = blockIdx.y * 128;
  const int bcol = blockIdx.x * 128;

  f32x4 acc[4][4];
#pragma unroll
  for (int m = 0; m < 4; ++m)
#pragma unroll
    for (int n = 0; n < 4; ++n)
      acc[m][n] = (f32x4){0.f, 0.f, 0.f, 0.f};

  // Staging: rows 0..63 (round 0) and 64..127 (round 1) of each 128x32 tile.
  // Thread t loads 16B chunk (t&3) of row (t>>2). LDS dest = linear, so
  // wave-uniform base + lane*16 matches exactly.
  const char* gA = (const char*)A + (size_t)(brow + (tid >> 2)) * (ND * 2) + (tid & 3) * 16;
  const char* gB = (const char*)V + (size_t)(bcol + (tid >> 2)) * (ND * 2) + (tid & 3) * 16;
  char* lA = (char*)As + wave * 1024;   // wave-uniform LDS base
  char* lB = (char*)Bs + wave * 1024;

  const char* aFragBase = (const char*)As + (wr * 64 + c16) * 64 + kq * 16;
  const char* bFragBase = (const char*)Bs + (wc * 64 + c16) * 64 + kq * 16;

  for (int kt = 0; kt < ND / 32; ++kt) {
    const int koff = kt * 64;  // byte offset within a 512B row
    GLDS16(gA + koff,            lA);
    GLDS16(gA + koff + 64 * 512, lA + 4096);
    GLDS16(gB + koff,            lB);
    GLDS16(gB + koff + 64 * 512, lB + 4096);
    __syncthreads();   // drains vmcnt (global_load_lds) + barrier

    bf16x8 af[4], bfv[4];
#pragma unroll
    for (int m = 0; m < 4; ++m)
      af[m] = *(const bf16x8*)(aFragBase + m * 16 * 64);
#pragma unroll
    for (int n = 0; n < 4; ++n)
      bfv[n] = *(const bf16x8*)(bFragBase + n * 16 * 64);
#pragma unroll
    for (int m = 0; m < 4; ++m)
#pragma unroll
      for (int n = 0; n < 4; ++n)
        acc[m][n] = __builtin_amdgcn_mfma_f32_16x16x32_bf16(af[m], bfv[n],
                                                            acc[m][n], 0, 0, 0);
    __syncthreads();   // protect LDS before next stage overwrites
  }

  // Epilogue: C/D layout col = lane&15, row = (lane>>4)*4 + reg.
#pragma unroll
  for (int m = 0; m < 4; ++m) {
#pragma unroll
    for (int r = 0; r < 4; ++r) {
      const int grow = brow + wr * 64 + m * 16 + kq * 4 + r;
      float* po = out + (size_t)grow * NC + (bcol + wc * 64 + c16);
      float s = 0.f;
#pragma unroll
      for (int n = 0; n < 4; ++n) {
        float v = acc[m][n][r];
        po[n * 16] = v;
        s += __expf(v);   // logits in [-1,1]: no max-subtraction needed
      }
      // reduce across the 16 col-lanes (same row)
      s += __shfl_xor(s, 1);
      s += __shfl_xor(s, 2);
      s += __shfl_xor(s, 4);
      s += __shfl_xor(s, 8);
      if (c16 == 0) atomicAdd(&rowsum[grow], s);
    }
  }
}

// loss = mean_i( log(rowsum[i]) - out[i, targets[i]] )
__global__ void finalize_kernel(const float* __restrict__ rowsum,
                                const float* __restrict__ out,  // d_out + 1
                                const int* __restrict__ targets,
                                float* __restrict__ loss) {
  int i = blockIdx.x * blockDim.x + threadIdx.x;
  float li = 0.f;
  if (i < NB) {
    float lse = logf(rowsum[i]);
    float xt  = out[(size_t)i * NC + targets[i]];
    li = lse - xt;
  }
#pragma unroll
  for (int o = 32; o > 0; o >>= 1) li += __shfl_down(li, o);
  __shared__ float wsum[4];
  int lane = threadIdx.x & 63, wv = threadIdx.x >> 6;
  if (lane == 0) wsum[wv] = li;
  __syncthreads();
  if (threadIdx.x == 0) {
    float s = wsum[0] + wsum[1] + wsum[2] + wsum[3];
    atomicAdd(loss, s * (1.0f / NB));
  }
}

extern "C" void kernel_launch(void* const* d_in, const int* in_sizes, int n_in,
                              void* d_out, int out_size, void* d_ws, size_t ws_size,
                              hipStream_t stream) {
  const float* inputs  = (const float*)d_in[0];
  const int*   targets = (const int*)d_in[1];
  // d_in[2] indexs, d_in[3] label_to_pairs, d_in[4] all_label_to_clusterid: unused (W_MS = 0)
  const float* V       = (const float*)d_in[5];

  float* loss    = (float*)d_out;          // output 0: scalar loss
  float* outputs = (float*)d_out + 1;      // output 1: [4096][32000]

  char* ws = (char*)d_ws;
  unsigned short* Abf = (unsigned short*)ws;                              // 2 MB
  unsigned short* Vbf = (unsigned short*)(ws + (size_t)NB * ND * 2);      // 16.4 MB
  float* rowsum = (float*)(ws + (size_t)NB * ND * 2 + (size_t)NC * ND * 2);

  hipLaunchKernelGGL(prep_kernel, dim3(2048), dim3(256), 0, stream,
                     inputs, V, Abf, Vbf, rowsum, loss);
  hipLaunchKernelGGL(gemm_expsum_kernel, dim3(NC / 128, NB / 128), dim3(256), 0, stream,
                     Abf, Vbf, outputs, rowsum);
  hipLaunchKernelGGL(finalize_kernel, dim3(NB / 256), dim3(256), 0, stream,
                     rowsum, outputs, targets, loss);
}

// Round 2
// 332.543 us; speedup vs baseline: 1.0893x; 1.0893x over previous
//
#include <hip/hip_runtime.h>
#include <hip/hip_bf16.h>
#include <stdint.h>

#define NB 4096
#define ND 256
#define NC 32000

typedef __bf16 bf16x8 __attribute__((ext_vector_type(8)));
typedef float  f32x4  __attribute__((ext_vector_type(4)));

__device__ __forceinline__ unsigned short f32_to_bf16(float f) {
  union { float f; uint32_t u; } v; v.f = f;
  uint32_t r = v.u + 0x7fffu + ((v.u >> 16) & 1u);
  return (unsigned short)(r >> 16);
}

// Cast inputs/V to bf16 in workspace; zero rowsum + loss accumulator.
__global__ void prep_kernel(const float* __restrict__ inA,
                            const float* __restrict__ inV,
                            unsigned short* __restrict__ outA,
                            unsigned short* __restrict__ outV,
                            float* __restrict__ rowsum,
                            float* __restrict__ loss) {
  int gid = blockIdx.x * blockDim.x + threadIdx.x;
  int stride = gridDim.x * blockDim.x;
  if (gid == 0) *loss = 0.f;
  for (int i = gid; i < NB; i += stride) rowsum[i] = 0.f;
  const int nA4 = NB * ND / 4;   // 262144
  const int nV4 = NC * ND / 4;   // 2048000
  for (int i = gid; i < nA4 + nV4; i += stride) {
    float4 v = (i < nA4) ? ((const float4*)inA)[i]
                         : ((const float4*)inV)[i - nA4];
    ushort4 o;
    o.x = f32_to_bf16(v.x);
    o.y = f32_to_bf16(v.y);
    o.z = f32_to_bf16(v.z);
    o.w = f32_to_bf16(v.w);
    if (i < nA4) ((ushort4*)outA)[i] = o;
    else         ((ushort4*)outV)[i - nA4] = o;
  }
}

// Barrier-free GEMM: 128x128 tile, 4 waves (2x2), each wave 64x64 via 4x4
// mfma 16x16x32 frags. A/B fragments loaded DIRECTLY from global (L2-hot:
// A = 2 MB total; V-tile shared by 32 consecutive blocks), register
// double-buffered over the 8 K-steps. No __syncthreads anywhere.
// Epilogue: per-wave LDS transpose -> coalesced float4 stores + exp-rowsum.
__global__ void __launch_bounds__(256)
gemm_expsum_kernel(const unsigned short* __restrict__ A,
                   const unsigned short* __restrict__ V,
                   float* __restrict__ out,     // d_out + 1
                   float* __restrict__ rowsum) {
  // per-wave 16x68 f32 transpose pad: write 2-way (free), read at b128 minimum
  __shared__ float tls[4][16][68];

  const int tid  = threadIdx.x;
  const int lane = tid & 63;
  const int wave = tid >> 6;
  const int wr   = wave >> 1;
  const int wc   = wave & 1;
  const int c16  = lane & 15;
  const int kq   = lane >> 4;      // 0..3

  // grid: x = row-tile (fast, 32) so consecutive blocks share the V col-tile
  const int brow = blockIdx.x * 128;
  const int bcol = blockIdx.y * 128;

  const __bf16* Ab = (const __bf16*)A;
  const __bf16* Vb = (const __bf16*)V;
  // lane's fragment base: row (c16), k-chunk kq*8
  const __bf16* aBase = Ab + (size_t)(brow + wr * 64 + c16) * ND + kq * 8;
  const __bf16* bBase = Vb + (size_t)(bcol + wc * 64 + c16) * ND + kq * 8;

  f32x4 acc[4][4];
#pragma unroll
  for (int m = 0; m < 4; ++m)
#pragma unroll
    for (int n = 0; n < 4; ++n)
      acc[m][n] = (f32x4){0.f, 0.f, 0.f, 0.f};

  bf16x8 a0[4], b0[4], a1[4], b1[4];

#define LOADF(AF, BF, KT)                                                     \
  do {                                                                        \
    _Pragma("unroll")                                                         \
    for (int m = 0; m < 4; ++m)                                               \
      AF[m] = *(const bf16x8*)(aBase + (size_t)m * 16 * ND + (KT) * 32);      \
    _Pragma("unroll")                                                         \
    for (int n = 0; n < 4; ++n)                                               \
      BF[n] = *(const bf16x8*)(bBase + (size_t)n * 16 * ND + (KT) * 32);      \
  } while (0)

#define MFMAALL(AF, BF)                                                       \
  do {                                                                        \
    _Pragma("unroll")                                                         \
    for (int m = 0; m < 4; ++m)                                               \
      _Pragma("unroll")                                                       \
      for (int n = 0; n < 4; ++n)                                             \
        acc[m][n] = __builtin_amdgcn_mfma_f32_16x16x32_bf16(AF[m], BF[n],     \
                                                            acc[m][n], 0, 0, 0); \
  } while (0)

  LOADF(a0, b0, 0);
#pragma unroll
  for (int kt = 0; kt < 8; kt += 2) {
    if (kt + 1 < 8) LOADF(a1, b1, kt + 1);
    MFMAALL(a0, b0);
    if (kt + 2 < 8) LOADF(a0, b0, kt + 2);
    MFMAALL(a1, b1);
  }

  // Epilogue: per-wave transpose through LDS, coalesced float4 stores,
  // fused exp-rowsum. Wave-synchronous (no __syncthreads).
#pragma unroll
  for (int m = 0; m < 4; ++m) {
#pragma unroll
    for (int n = 0; n < 4; ++n)
#pragma unroll
      for (int r = 0; r < 4; ++r)
        tls[wave][kq * 4 + r][n * 16 + c16] = acc[m][n][r];
    asm volatile("s_waitcnt lgkmcnt(0)" ::: "memory");
    __builtin_amdgcn_sched_barrier(0);
#pragma unroll
    for (int rr = 0; rr < 4; ++rr) {
      const int lr = rr * 4 + kq;
      float4 v = *(const float4*)&tls[wave][lr][c16 * 4];
      const int grow = brow + wr * 64 + m * 16 + lr;
      *(float4*)(out + (size_t)grow * NC + bcol + wc * 64 + c16 * 4) = v;
      float s = __expf(v.x) + __expf(v.y) + __expf(v.z) + __expf(v.w);
      s += __shfl_xor(s, 1);
      s += __shfl_xor(s, 2);
      s += __shfl_xor(s, 4);
      s += __shfl_xor(s, 8);
      if (c16 == 0) atomicAdd(&rowsum[grow], s);
    }
    asm volatile("s_waitcnt lgkmcnt(0)" ::: "memory");
    __builtin_amdgcn_sched_barrier(0);
  }
#undef LOADF
#undef MFMAALL
}

// loss = mean_i( log(rowsum[i]) - out[i, targets[i]] )
__global__ void finalize_kernel(const float* __restrict__ rowsum,
                                const float* __restrict__ out,  // d_out + 1
                                const int* __restrict__ targets,
                                float* __restrict__ loss) {
  int i = blockIdx.x * blockDim.x + threadIdx.x;
  float li = 0.f;
  if (i < NB) {
    float lse = logf(rowsum[i]);
    float xt  = out[(size_t)i * NC + targets[i]];
    li = lse - xt;
  }
#pragma unroll
  for (int o = 32; o > 0; o >>= 1) li += __shfl_down(li, o);
  __shared__ float wsum[4];
  int lane = threadIdx.x & 63, wv = threadIdx.x >> 6;
  if (lane == 0) wsum[wv] = li;
  __syncthreads();
  if (threadIdx.x == 0) {
    float s = wsum[0] + wsum[1] + wsum[2] + wsum[3];
    atomicAdd(loss, s * (1.0f / NB));
  }
}

extern "C" void kernel_launch(void* const* d_in, const int* in_sizes, int n_in,
                              void* d_out, int out_size, void* d_ws, size_t ws_size,
                              hipStream_t stream) {
  const float* inputs  = (const float*)d_in[0];
  const int*   targets = (const int*)d_in[1];
  // d_in[2] indexs, d_in[3] label_to_pairs, d_in[4] all_label_to_clusterid: unused (W_MS = 0)
  const float* V       = (const float*)d_in[5];

  float* loss    = (float*)d_out;          // output 0: scalar loss
  float* outputs = (float*)d_out + 1;      // output 1: [4096][32000]

  char* ws = (char*)d_ws;
  unsigned short* Abf = (unsigned short*)ws;                              // 2 MB
  unsigned short* Vbf = (unsigned short*)(ws + (size_t)NB * ND * 2);      // 16.4 MB
  float* rowsum = (float*)(ws + (size_t)NB * ND * 2 + (size_t)NC * ND * 2);

  hipLaunchKernelGGL(prep_kernel, dim3(2048), dim3(256), 0, stream,
                     inputs, V, Abf, Vbf, rowsum, loss);
  // grid.x = row-tiles (32, fast-varying) -> consecutive blocks share V col-tile
  hipLaunchKernelGGL(gemm_expsum_kernel, dim3(NB / 128, NC / 128), dim3(256), 0, stream,
                     Abf, Vbf, outputs, rowsum);
  hipLaunchKernelGGL(finalize_kernel, dim3(NB / 256), dim3(256), 0, stream,
                     rowsum, outputs, targets, loss);
}

// Round 3
// 328.594 us; speedup vs baseline: 1.1024x; 1.0120x over previous
//
#include <hip/hip_runtime.h>
#include <hip/hip_bf16.h>
#include <stdint.h>

#define NB 4096
#define ND 256
#define NC 32000

typedef __bf16 bf16x8 __attribute__((ext_vector_type(8)));
typedef float  f32x4  __attribute__((ext_vector_type(4)));

__device__ __forceinline__ unsigned short f32_to_bf16(float f) {
  union { float f; uint32_t u; } v; v.f = f;
  uint32_t r = v.u + 0x7fffu + ((v.u >> 16) & 1u);
  return (unsigned short)(r >> 16);
}

// Cast inputs/V to bf16 in workspace; zero rowsum + loss accumulator.
__global__ void prep_kernel(const float* __restrict__ inA,
                            const float* __restrict__ inV,
                            unsigned short* __restrict__ outA,
                            unsigned short* __restrict__ outV,
                            float* __restrict__ rowsum,
                            float* __restrict__ loss) {
  int gid = blockIdx.x * blockDim.x + threadIdx.x;
  int stride = gridDim.x * blockDim.x;
  if (gid == 0) *loss = 0.f;
  for (int i = gid; i < NB; i += stride) rowsum[i] = 0.f;
  const int nA4 = NB * ND / 4;   // 262144
  const int nV4 = NC * ND / 4;   // 2048000
  for (int i = gid; i < nA4 + nV4; i += stride) {
    float4 v = (i < nA4) ? ((const float4*)inA)[i]
                         : ((const float4*)inV)[i - nA4];
    ushort4 o;
    o.x = f32_to_bf16(v.x);
    o.y = f32_to_bf16(v.y);
    o.z = f32_to_bf16(v.z);
    o.w = f32_to_bf16(v.w);
    if (i < nA4) ((ushort4*)outA)[i] = o;
    else         ((ushort4*)outV)[i - nA4] = o;
  }
}

// Barrier-free GEMM: 128x128 tile, 4 waves (2x2), each wave 64x64 via 4x4
// mfma 16x16x32 frags. A/B fragments loaded DIRECTLY from global (L2-hot),
// register double-buffered over the 8 K-steps. No __syncthreads anywhere.
// __launch_bounds__(256, 2): allow ~256 VGPRs/wave so acc[16] + both operand
// buffers stay register-resident (R2's 68-VGPR allocation serialized every
// MFMA behind a global load).
__global__ void __launch_bounds__(256, 2)
gemm_expsum_kernel(const unsigned short* __restrict__ A,
                   const unsigned short* __restrict__ V,
                   float* __restrict__ out,     // d_out + 1
                   float* __restrict__ rowsum) {
  // per-wave 16x68 f32 transpose pad: write 2-way (free), read at b128 minimum
  __shared__ float tls[4][16][68];

  const int tid  = threadIdx.x;
  const int lane = tid & 63;
  const int wave = tid >> 6;
  const int wr   = wave >> 1;
  const int wc   = wave & 1;
  const int c16  = lane & 15;
  const int kq   = lane >> 4;      // 0..3

  // grid: x = row-tile (fast, 32) so consecutive blocks share the V col-tile
  const int brow = blockIdx.x * 128;
  const int bcol = blockIdx.y * 128;

  const __bf16* Ab = (const __bf16*)A;
  const __bf16* Vb = (const __bf16*)V;
  // lane's fragment base: row (c16), k-chunk kq*8
  const __bf16* aBase = Ab + (size_t)(brow + wr * 64 + c16) * ND + kq * 8;
  const __bf16* bBase = Vb + (size_t)(bcol + wc * 64 + c16) * ND + kq * 8;

  f32x4 acc[4][4];
#pragma unroll
  for (int m = 0; m < 4; ++m)
#pragma unroll
    for (int n = 0; n < 4; ++n)
      acc[m][n] = (f32x4){0.f, 0.f, 0.f, 0.f};

  bf16x8 a0[4], b0[4], a1[4], b1[4];

#define LOADF(AF, BF, KT)                                                     \
  do {                                                                        \
    _Pragma("unroll")                                                         \
    for (int m = 0; m < 4; ++m)                                               \
      AF[m] = *(const bf16x8*)(aBase + (size_t)m * 16 * ND + (KT) * 32);      \
    _Pragma("unroll")                                                         \
    for (int n = 0; n < 4; ++n)                                               \
      BF[n] = *(const bf16x8*)(bBase + (size_t)n * 16 * ND + (KT) * 32);      \
  } while (0)

#define MFMAALL(AF, BF)                                                       \
  do {                                                                        \
    _Pragma("unroll")                                                         \
    for (int m = 0; m < 4; ++m)                                               \
      _Pragma("unroll")                                                       \
      for (int n = 0; n < 4; ++n)                                             \
        acc[m][n] = __builtin_amdgcn_mfma_f32_16x16x32_bf16(AF[m], BF[n],     \
                                                            acc[m][n], 0, 0, 0); \
  } while (0)

  LOADF(a0, b0, 0);
#pragma unroll
  for (int kt = 0; kt < 8; kt += 2) {
    if (kt + 1 < 8) LOADF(a1, b1, kt + 1);
    MFMAALL(a0, b0);
    if (kt + 2 < 8) LOADF(a0, b0, kt + 2);
    MFMAALL(a1, b1);
  }

  // Epilogue: per-wave transpose through LDS, coalesced float4 stores,
  // fused exp-rowsum. Wave-synchronous (no __syncthreads).
#pragma unroll
  for (int m = 0; m < 4; ++m) {
#pragma unroll
    for (int n = 0; n < 4; ++n)
#pragma unroll
      for (int r = 0; r < 4; ++r)
        tls[wave][kq * 4 + r][n * 16 + c16] = acc[m][n][r];
    asm volatile("s_waitcnt lgkmcnt(0)" ::: "memory");
    __builtin_amdgcn_sched_barrier(0);
#pragma unroll
    for (int rr = 0; rr < 4; ++rr) {
      const int lr = rr * 4 + kq;
      float4 v = *(const float4*)&tls[wave][lr][c16 * 4];
      const int grow = brow + wr * 64 + m * 16 + lr;
      *(float4*)(out + (size_t)grow * NC + bcol + wc * 64 + c16 * 4) = v;
      float s = __expf(v.x) + __expf(v.y) + __expf(v.z) + __expf(v.w);
      s += __shfl_xor(s, 1);
      s += __shfl_xor(s, 2);
      s += __shfl_xor(s, 4);
      s += __shfl_xor(s, 8);
      if (c16 == 0) atomicAdd(&rowsum[grow], s);
    }
    asm volatile("s_waitcnt lgkmcnt(0)" ::: "memory");
    __builtin_amdgcn_sched_barrier(0);
  }
#undef LOADF
#undef MFMAALL
}

// loss = mean_i( log(rowsum[i]) - out[i, targets[i]] )
__global__ void finalize_kernel(const float* __restrict__ rowsum,
                                const float* __restrict__ out,  // d_out + 1
                                const int* __restrict__ targets,
                                float* __restrict__ loss) {
  int i = blockIdx.x * blockDim.x + threadIdx.x;
  float li = 0.f;
  if (i < NB) {
    float lse = logf(rowsum[i]);
    float xt  = out[(size_t)i * NC + targets[i]];
    li = lse - xt;
  }
#pragma unroll
  for (int o = 32; o > 0; o >>= 1) li += __shfl_down(li, o);
  __shared__ float wsum[4];
  int lane = threadIdx.x & 63, wv = threadIdx.x >> 6;
  if (lane == 0) wsum[wv] = li;
  __syncthreads();
  if (threadIdx.x == 0) {
    float s = wsum[0] + wsum[1] + wsum[2] + wsum[3];
    atomicAdd(loss, s * (1.0f / NB));
  }
}

extern "C" void kernel_launch(void* const* d_in, const int* in_sizes, int n_in,
                              void* d_out, int out_size, void* d_ws, size_t ws_size,
                              hipStream_t stream) {
  const float* inputs  = (const float*)d_in[0];
  const int*   targets = (const int*)d_in[1];
  // d_in[2] indexs, d_in[3] label_to_pairs, d_in[4] all_label_to_clusterid: unused (W_MS = 0)
  const float* V       = (const float*)d_in[5];

  float* loss    = (float*)d_out;          // output 0: scalar loss
  float* outputs = (float*)d_out + 1;      // output 1: [4096][32000]

  char* ws = (char*)d_ws;
  unsigned short* Abf = (unsigned short*)ws;                              // 2 MB
  unsigned short* Vbf = (unsigned short*)(ws + (size_t)NB * ND * 2);      // 16.4 MB
  float* rowsum = (float*)(ws + (size_t)NB * ND * 2 + (size_t)NC * ND * 2);

  hipLaunchKernelGGL(prep_kernel, dim3(2048), dim3(256), 0, stream,
                     inputs, V, Abf, Vbf, rowsum, loss);
  // grid.x = row-tiles (32, fast-varying) -> consecutive blocks share V col-tile
  hipLaunchKernelGGL(gemm_expsum_kernel, dim3(NB / 128, NC / 128), dim3(256), 0, stream,
                     Abf, Vbf, outputs, rowsum);
  hipLaunchKernelGGL(finalize_kernel, dim3(NB / 256), dim3(256), 0, stream,
                     rowsum, outputs, targets, loss);
}